// Round 8
// baseline (584.682 us; speedup 1.0000x reference)
//
#include <hip/hip_runtime.h>

#define KSTATES 64

__device__ __forceinline__ float wave_max64(float v) {
#pragma unroll
  for (int off = 32; off; off >>= 1) v = fmaxf(v, __shfl_xor(v, off, 64));
  return v;
}

__device__ __forceinline__ float wave_sum64(float v) {
#pragma unroll
  for (int off = 32; off; off >>= 1) v += __shfl_xor(v, off, 64);
  return v;
}

__device__ __forceinline__ float bcast0(float v) {
  return __int_as_float(__builtin_amdgcn_readfirstlane(__float_as_int(v)));
}

// Exactly 1 wave/EU: 512 single-wave blocks on 256 CUs = 2 waves/CU, so
// occupancy is structurally irrelevant. Full VGPR file keeps c[64], the
// emission ring, AND 16 in-flight float4 LDS reads register-resident.
__global__ __launch_bounds__(64)
__attribute__((amdgpu_waves_per_eu(1, 1))) void crf_kernel(
    const float* __restrict__ emissions,   // [B, T, K]
    const float* __restrict__ transitions, // [K, K]
    const float* __restrict__ start_trans, // [K]
    const float* __restrict__ end_trans,   // [K]
    const int* __restrict__ labels,        // [B, T]
    const int* __restrict__ sent_len,      // [B]
    float* __restrict__ out,               // scalar
    int T, float inv_B) {
  const int b = blockIdx.x;
  const int j = threadIdx.x;  // state index == lane
  const int sl = sent_len[b];
  const int tmax = T - 1;

  __shared__ float Abuf[2][KSTATES];

  const float* em = emissions + (size_t)b * T * KSTATES;
  const int* lbl = labels + (size_t)b * T;

  // ---- gold score: lane-parallel over time (independent, pipelined) ----
  float g = 0.f;
#pragma unroll 4
  for (int t0 = j; t0 < T; t0 += KSTATES) {
    if (t0 < sl) {
      int lab = lbl[t0];
      float v = em[(size_t)t0 * KSTATES + lab];
      if (t0 == 0)
        v += start_trans[lab];
      else
        v += transitions[lbl[t0 - 1] * KSTATES + lab];
      if (t0 == sl - 1) v += end_trans[lab];
      g += v;
    }
  }
  float gold = wave_sum64(g);

  // ---- c[i] = exp(T[i][j]) : column j of exp(transitions) (stays in VGPRs)
  float c[KSTATES];
#pragma unroll
  for (int i = 0; i < KSTATES; ++i) c[i] = __expf(transitions[i * KSTATES + j]);

  // ---- forward scan: exp-space linear recurrence, LDS-broadcast matvec ----
  const float* emj = em + j;
  float e0 = emj[0];
  float alpha0 = start_trans[j] + e0;
  float m0 = wave_max64(alpha0);
  float a = __expf(alpha0 - m0);  // linear-space, normalized
  float C = m0;                   // log offset
  float r = 1.0f;                 // pending renormalizer (applied exactly once)

  float ring[8];
#pragma unroll
  for (int q = 0; q < 8; ++q) ring[q] = emj[(size_t)min(1 + q, tmax) * KSTATES];

  for (int t = 1; t < sl; t += 8) {
#pragma unroll
    for (int q = 0; q < 8; ++q) {
      if (t + q < sl) {  // sl is wave-uniform -> scalar branch, no divergence
        float emit = ring[q];
        ring[q] = emj[(size_t)min(t + q + 8, tmax) * KSTATES];

        float E = __expf(emit);
        if (q == 0 || q == 4) {  // apply pending renorm exactly once
          E *= r;
          r = 1.0f;
        }

        // publish a, then broadcast-read the whole vector as 16 float4's.
        // All lanes read the same addresses (same-address broadcast = no
        // bank conflicts). Loads go into 16 resident temporaries so the
        // 16 ds_read_b128 stay in flight (progressive lgkmcnt), then the
        // FMA block consumes them in issue order.
        float* buf = Abuf[t & 1];
        buf[j] = a;
        __builtin_amdgcn_wave_barrier();
        const float4* Av = (const float4*)buf;
        float4 v[16];
#pragma unroll
        for (int p = 0; p < 16; ++p) v[p] = Av[p];

        float acc0 = 0.f, acc1 = 0.f, acc2 = 0.f, acc3 = 0.f;
#pragma unroll
        for (int p = 0; p < 16; ++p) {
          acc0 = fmaf(v[p].x, c[4 * p + 0], acc0);
          acc1 = fmaf(v[p].y, c[4 * p + 1], acc1);
          acc2 = fmaf(v[p].z, c[4 * p + 2], acc2);
          acc3 = fmaf(v[p].w, c[4 * p + 3], acc3);
        }
        float s = (acc0 + acc1) + (acc2 + acc3);
        a = s * E;

        if (q == 3 || q == 7) {  // renorm every 4 steps (off critical path)
          float ar = bcast0(a);
          C += __logf(ar);
          r = __builtin_amdgcn_rcpf(ar);
        }
      }
    }
  }

  // fwd = logsumexp(alpha + end); pending r folded in here
  float v = a * __expf(end_trans[j]);
  float sum = wave_sum64(v);
  float fwd = C + __logf(sum * r);

  if (j == 0) atomicAdd(out, (fwd - gold) * inv_B);
}

extern "C" void kernel_launch(void* const* d_in, const int* in_sizes, int n_in,
                              void* d_out, int out_size, void* d_ws, size_t ws_size,
                              hipStream_t stream) {
  const float* emissions = (const float*)d_in[0];
  const float* transitions = (const float*)d_in[1];
  const float* start_trans = (const float*)d_in[2];
  const float* end_trans = (const float*)d_in[3];
  const int* labels = (const int*)d_in[4];
  const int* sent_len = (const int*)d_in[5];
  float* out = (float*)d_out;

  const int B = in_sizes[5];
  const int T = in_sizes[4] / B;

  hipMemsetAsync(out, 0, sizeof(float), stream);
  crf_kernel<<<B, KSTATES, 0, stream>>>(
      emissions, transitions, start_trans, end_trans, labels, sent_len, out, T,
      1.0f / (float)B);
}

// Round 9
// 526.338 us; speedup vs baseline: 1.1108x; 1.1108x over previous
//
#include <hip/hip_runtime.h>

#define KSTATES 64

__device__ __forceinline__ float wave_max64(float v) {
#pragma unroll
  for (int off = 32; off; off >>= 1) v = fmaxf(v, __shfl_xor(v, off, 64));
  return v;
}

__device__ __forceinline__ float wave_sum64(float v) {
#pragma unroll
  for (int off = 32; off; off >>= 1) v += __shfl_xor(v, off, 64);
  return v;
}

__device__ __forceinline__ float bcast0(float v) {
  return __int_as_float(__builtin_amdgcn_readfirstlane(__float_as_int(v)));
}

// Exactly 1 wave/EU: 512 single-wave blocks on 256 CUs = 2 waves/CU, so
// occupancy is structurally irrelevant. Register budget is sized so the
// exp(transitions) column (64), both emission rings (16), and state fit
// WITHOUT pressure — pressure is what made the scheduler sink the ring's
// global loads to their use sites in R1-R8 (one exposed HBM latency/step).
__global__ __launch_bounds__(64)
__attribute__((amdgpu_waves_per_eu(1, 1))) void crf_kernel(
    const float* __restrict__ emissions,   // [B, T, K]
    const float* __restrict__ transitions, // [K, K]
    const float* __restrict__ start_trans, // [K]
    const float* __restrict__ end_trans,   // [K]
    const int* __restrict__ labels,        // [B, T]
    const int* __restrict__ sent_len,      // [B]
    float* __restrict__ out,               // scalar
    int T, float inv_B) {
  const int b = blockIdx.x;
  const int j = threadIdx.x;  // state index == lane
  const int sl = sent_len[b];
  const int tmax = T - 1;

  __shared__ float Abuf[2][KSTATES];

  const float* em = emissions + (size_t)b * T * KSTATES;
  const int* lbl = labels + (size_t)b * T;

  // ---- gold score: lane-parallel over time (independent, pipelined) ----
  float g = 0.f;
#pragma unroll 4
  for (int t0 = j; t0 < T; t0 += KSTATES) {
    if (t0 < sl) {
      int lab = lbl[t0];
      float v = em[(size_t)t0 * KSTATES + lab];
      if (t0 == 0)
        v += start_trans[lab];
      else
        v += transitions[lbl[t0 - 1] * KSTATES + lab];
      if (t0 == sl - 1) v += end_trans[lab];
      g += v;
    }
  }
  float gold = wave_sum64(g);

  // ---- c[i] = exp(T[i][j]) : column j of exp(transitions) (stays in VGPRs)
  float c[KSTATES];
#pragma unroll
  for (int i = 0; i < KSTATES; ++i) c[i] = __expf(transitions[i * KSTATES + j]);

  // ---- forward scan: exp-space linear recurrence, LDS-broadcast matvec ----
  const float* emj = em + j;
  float e0 = emj[0];
  float alpha0 = start_trans[j] + e0;
  float m0 = wave_max64(alpha0);
  float a = __expf(alpha0 - m0);  // linear-space, normalized
  float C = m0;                   // log offset
  float r = 1.0f;                 // pending renormalizer (applied exactly once)

  // ring = current chunk's emissions; nring = next chunk's, batch-issued at
  // the top of the current chunk (slack = one full chunk >> HBM latency).
  float ring[8];
#pragma unroll
  for (int q = 0; q < 8; ++q) ring[q] = emj[(size_t)min(1 + q, tmax) * KSTATES];

  for (int t = 1; t < sl; t += 8) {
    float nring[8];
#pragma unroll
    for (int q = 0; q < 8; ++q)
      nring[q] = emj[(size_t)min(t + 8 + q, tmax) * KSTATES];

#pragma unroll
    for (int q = 0; q < 8; ++q) {
      if (t + q < sl) {  // sl is wave-uniform -> scalar branch, no divergence
        float emit = ring[q];

        float E = __expf(emit);
        if (q == 0 || q == 4) {  // apply pending renorm exactly once
          E *= r;
          r = 1.0f;
        }

        // publish a, broadcast-read as float4's, consume immediately
        // (in-order LDS returns -> progressive lgkmcnt; reads run ahead).
        float* buf = Abuf[(t + q) & 1];
        buf[j] = a;
        __builtin_amdgcn_wave_barrier();
        const float4* Av = (const float4*)buf;
        float acc0 = 0.f, acc1 = 0.f, acc2 = 0.f, acc3 = 0.f;
#pragma unroll
        for (int p = 0; p < 16; ++p) {
          float4 v = Av[p];
          acc0 = fmaf(v.x, c[4 * p + 0], acc0);
          acc1 = fmaf(v.y, c[4 * p + 1], acc1);
          acc2 = fmaf(v.z, c[4 * p + 2], acc2);
          acc3 = fmaf(v.w, c[4 * p + 3], acc3);
        }
        float s = (acc0 + acc1) + (acc2 + acc3);
        a = s * E;

        if (q == 3 || q == 7) {  // renorm every 4 steps (off critical path)
          float ar = bcast0(a);
          C += __logf(ar);
          r = __builtin_amdgcn_rcpf(ar);
        }
      }
    }

#pragma unroll
    for (int q = 0; q < 8; ++q) ring[q] = nring[q];
  }

  // fwd = logsumexp(alpha + end); pending r folded in here
  float v = a * __expf(end_trans[j]);
  float sum = wave_sum64(v);
  float fwd = C + __logf(sum * r);

  if (j == 0) atomicAdd(out, (fwd - gold) * inv_B);
}

extern "C" void kernel_launch(void* const* d_in, const int* in_sizes, int n_in,
                              void* d_out, int out_size, void* d_ws, size_t ws_size,
                              hipStream_t stream) {
  const float* emissions = (const float*)d_in[0];
  const float* transitions = (const float*)d_in[1];
  const float* start_trans = (const float*)d_in[2];
  const float* end_trans = (const float*)d_in[3];
  const int* labels = (const int*)d_in[4];
  const int* sent_len = (const int*)d_in[5];
  float* out = (float*)d_out;

  const int B = in_sizes[5];
  const int T = in_sizes[4] / B;

  hipMemsetAsync(out, 0, sizeof(float), stream);
  crf_kernel<<<B, KSTATES, 0, stream>>>(
      emissions, transitions, start_trans, end_trans, labels, sent_len, out, T,
      1.0f / (float)B);
}